// Round 5
// baseline (148.652 us; speedup 1.0000x reference)
//
#include <hip/hip_runtime.h>
#include <hip/hip_cooperative_groups.h>

namespace cg = cooperative_groups;

typedef __bf16 bf16;
typedef __bf16 bf16x4 __attribute__((ext_vector_type(4)));
typedef __bf16 bf16x8 __attribute__((ext_vector_type(8)));
typedef float f32x4 __attribute__((ext_vector_type(4)));

#define NTOK 32768
#define SCALE_F 0.17677669529663689f

// ============ K1: k/v proj (transposed) + exp(k) + ctx^T + S1, atomic-reduced ============
// grid (64, 8b), 256 thr, 8 subtiles of 64 tokens. Prefetched x loads, native bf16 casts.
__global__ __launch_bounds__(256) void k1_ctx(const float* __restrict__ x,
    const float* __restrict__ wqkv, float* __restrict__ ctx, float* __restrict__ s1)
{
  const int b = blockIdx.y, chunk = blockIdx.x;
  const int t = threadIdx.x, w = t>>6, l = t&63, lr = l&15, lg = l>>4;
  __shared__ bf16 xT[64*72];    // [n][c]
  __shared__ bf16 ek[128*72];   // [k-ch][n]  exp(k)
  __shared__ bf16 vl[128*72];   // [v-ch][n]  v

  // B-frags: wqkv rows 128 + w*64 + ct*16 + lr
  bf16x8 bw[4][2];
  #pragma unroll
  for (int ct=0;ct<4;ct++)
    #pragma unroll
    for (int ks=0;ks<2;ks++){
      const float* src = wqkv + (128 + w*64 + ct*16 + lr)*64 + ks*32 + lg*8;
      #pragma unroll
      for (int j=0;j<8;j++) bw[ct][ks][j] = (bf16)src[j];
    }
  bf16x8 ones;
  #pragma unroll
  for (int j=0;j<8;j++) ones[j] = (bf16)1.0f;

  f32x4 ctxa[2][2]; f32x4 s1a[2];
  #pragma unroll
  for (int i=0;i<2;i++){
    s1a[i] = f32x4{0.f,0.f,0.f,0.f};
    #pragma unroll
    for (int j=0;j<2;j++) ctxa[i][j] = f32x4{0.f,0.f,0.f,0.f};
  }
  const float* xb = x + (long)b*64*NTOK;
  bf16* dst = (w<2) ? ek : vl;
  const int chb = (w&1)*64;
  const bool isk = (w<2);
  const int sn = t&63, cg16 = (t>>6)*16;

  // prologue: prefetch subtile 0 (cvt to bf16 in regs)
  bf16x8 t0, t1;
  {
    const int n0 = chunk*512;
    #pragma unroll
    for (int i=0;i<8;i++) t0[i] = (bf16)xb[(long)(cg16+i)*NTOK + n0 + sn];
    #pragma unroll
    for (int i=0;i<8;i++) t1[i] = (bf16)xb[(long)(cg16+8+i)*NTOK + n0 + sn];
  }

  for (int s=0; s<8; s++) {
    *(bf16x8*)&xT[sn*72 + cg16]     = t0;
    *(bf16x8*)&xT[sn*72 + cg16 + 8] = t1;
    __syncthreads();
    if (s+1 < 8){
      const int n0 = chunk*512 + (s+1)*64;
      #pragma unroll
      for (int i=0;i<8;i++) t0[i] = (bf16)xb[(long)(cg16+i)*NTOK + n0 + sn];
      #pragma unroll
      for (int i=0;i<8;i++) t1[i] = (bf16)xb[(long)(cg16+8+i)*NTOK + n0 + sn];
    }
    f32x4 acc[4][4];
    #pragma unroll
    for (int rt=0;rt<4;rt++)
      #pragma unroll
      for (int ct=0;ct<4;ct++) acc[rt][ct] = f32x4{0.f,0.f,0.f,0.f};
    #pragma unroll
    for (int ks=0;ks<2;ks++){
      bf16x8 af[4];
      #pragma unroll
      for (int rt=0;rt<4;rt++)
        af[rt] = *(const bf16x8*)&xT[(rt*16+lr)*72 + ks*32 + lg*8];
      #pragma unroll
      for (int rt=0;rt<4;rt++)
        #pragma unroll
        for (int ct=0;ct<4;ct++)
          acc[rt][ct] = __builtin_amdgcn_mfma_f32_16x16x32_bf16(af[rt], bw[ct][ks], acc[rt][ct], 0,0,0);
    }
    // D[row=n=rt*16+lg*4+ri][col=ch=ct*16+lr]: b64 stores along n
    #pragma unroll
    for (int ct=0;ct<4;ct++){
      const int row = chb + ct*16 + lr;
      #pragma unroll
      for (int rt=0;rt<4;rt++){
        bf16x4 p;
        #pragma unroll
        for (int ri=0;ri<4;ri++){
          const float v = acc[rt][ct][ri];
          p[ri] = isk ? (bf16)__expf(v) : (bf16)v;
        }
        *(bf16x4*)&dst[row*72 + rt*16 + lg*4] = p;
      }
    }
    __syncthreads();
    // ctx^T[e][d] += v[e][n]*ek[d][n]; S1[d] via ones-row MFMA
    #pragma unroll
    for (int ks=0;ks<2;ks++){
      bf16x8 bd[2];
      #pragma unroll
      for (int cd=0;cd<2;cd++)
        bd[cd] = *(const bf16x8*)&ek[(w*32 + cd*16 + lr)*72 + ks*32 + lg*8];
      #pragma unroll
      for (int re=0;re<2;re++){
        bf16x8 a = *(const bf16x8*)&vl[(w*32 + re*16 + lr)*72 + ks*32 + lg*8];
        #pragma unroll
        for (int cd=0;cd<2;cd++)
          ctxa[re][cd] = __builtin_amdgcn_mfma_f32_16x16x32_bf16(a, bd[cd], ctxa[re][cd], 0,0,0);
      }
      #pragma unroll
      for (int cd=0;cd<2;cd++)
        s1a[cd] = __builtin_amdgcn_mfma_f32_16x16x32_bf16(ones, bd[cd], s1a[cd], 0,0,0);
    }
  }
  float* cp = ctx + ((long)b*4 + w)*1024;
  #pragma unroll
  for (int re=0;re<2;re++)
    #pragma unroll
    for (int cd=0;cd<2;cd++)
      #pragma unroll
      for (int ri=0;ri<4;ri++){
        const int e = re*16 + lg*4 + ri, d = cd*16 + lr;
        atomicAdd(&cp[e*32 + d], ctxa[re][cd][ri]);
      }
  if (lg==0){
    #pragma unroll
    for (int cd=0;cd<2;cd++)
      atomicAdd(&s1[(long)b*128 + w*32 + cd*16 + lr], s1a[cd][0]);
  }
}

// ============ K2: build W2 = SCALE*w_out*ctx^T/S1 ============
__global__ __launch_bounds__(256) void k2_w2(const float* __restrict__ ctx,
    const float* __restrict__ s1, const float* __restrict__ wout, bf16* __restrict__ W2)
{
  const int b = blockIdx.y, h = blockIdx.x, t = threadIdx.x;
  __shared__ float cs[1024];
  __shared__ float s1s[32];
  {
    f32x4 p4 = *(const f32x4*)(ctx + ((long)b*4 + h)*1024 + t*4);
    *(f32x4*)&cs[t*4] = p4;
  }
  if (t < 32) s1s[t] = s1[(long)b*128 + h*32 + t];
  __syncthreads();
  const int d = t & 31;
  const float rinv = SCALE_F / s1s[d];
  #pragma unroll
  for (int oi=0; oi<8; oi++){
    const int o = (t>>5)*8 + oi;
    float acc = 0.f;
    #pragma unroll
    for (int e=0;e<32;e++) acc += wout[o*128 + h*32 + e] * cs[e*32 + d];
    W2[((long)b*64 + o)*128 + h*32 + d] = (bf16)(acc * rinv);
  }
}

// ============ K3 body: q-proj + softmax_D + y = W2@qsm + b_out, fused norm ============
// grid (64, 8b), 256 thr, 8 token-tiles of 64 per block, y kept in registers.
// COOP: grid.sync -> normalize in-reg -> final out.  !COOP: write raw y + partials.
template<bool COOP>
__device__ __forceinline__ void k3_body(const float* __restrict__ x,
    const float* __restrict__ wqkv, const bf16* __restrict__ W2g,
    const float* __restrict__ bout, float* __restrict__ out,
    float* __restrict__ yacc, const float* __restrict__ gamma,
    const float* __restrict__ beta, float* __restrict__ ysum)
{
  const int b = blockIdx.y, blk = blockIdx.x;
  const int t = threadIdx.x, w = t>>6, l = t&63, lr = l&15, lg = l>>4;
  __shared__ bf16 W2s[64*136];
  __shared__ bf16 xT[64*72];
  __shared__ bf16 qs[64*136];
  __shared__ float red[8];
  const float* xb = x + (long)b*64*NTOK;
  float* yb = out + (long)b*64*NTOK;

  bf16x8 qfr[2][2];   // q rows w*32 .. w*32+31
  #pragma unroll
  for (int rt=0;rt<2;rt++)
    #pragma unroll
    for (int ks=0;ks<2;ks++){
      const float* src = wqkv + (w*32 + rt*16 + lr)*64 + ks*32 + lg*8;
      #pragma unroll
      for (int j=0;j<8;j++) qfr[rt][ks][j] = (bf16)src[j];
    }
  { // stage W2[b] -> LDS once
    const bf16* src = W2g + (long)b*8192 + t*32;
    const int o = t>>2, c0 = (t&3)*32;
    #pragma unroll
    for (int k=0;k<4;k++)
      *(bf16x8*)&W2s[o*136 + c0 + k*8] = *(const bf16x8*)(src + k*8);
  }
  float boutr[16];
  #pragma unroll
  for (int rt=0;rt<4;rt++)
    #pragma unroll
    for (int ri=0;ri<4;ri++) boutr[rt*4+ri] = bout[rt*16 + lg*4 + ri];

  const int sn = t&63, cg16 = (t>>6)*16;
  bf16x8 t0, t1;
  {
    const int n0 = blk*512;
    #pragma unroll
    for (int i=0;i<8;i++) t0[i] = (bf16)xb[(long)(cg16+i)*NTOK + n0 + sn];
    #pragma unroll
    for (int i=0;i<8;i++) t1[i] = (bf16)xb[(long)(cg16+8+i)*NTOK + n0 + sn];
  }
  f32x4 yv[8][4];
  #pragma unroll
  for (int ti=0;ti<8;ti++)
    #pragma unroll
    for (int rt=0;rt<4;rt++) yv[ti][rt] = f32x4{0.f,0.f,0.f,0.f};
  float sum=0.f, ss=0.f;

  #pragma unroll
  for (int ti=0; ti<8; ti++){
    const int n0 = blk*512 + ti*64;
    *(bf16x8*)&xT[sn*72 + cg16]     = t0;
    *(bf16x8*)&xT[sn*72 + cg16 + 8] = t1;
    __syncthreads();   // xT (+W2s on ti=0) ready
    if (ti+1 < 8){
      const int nn0 = n0 + 64;
      #pragma unroll
      for (int i=0;i<8;i++) t0[i] = (bf16)xb[(long)(cg16+i)*NTOK + nn0 + sn];
      #pragma unroll
      for (int i=0;i<8;i++) t1[i] = (bf16)xb[(long)(cg16+8+i)*NTOK + nn0 + sn];
    }
    f32x4 qa[2][4];
    #pragma unroll
    for (int rt=0;rt<2;rt++)
      #pragma unroll
      for (int ct=0;ct<4;ct++) qa[rt][ct] = f32x4{0.f,0.f,0.f,0.f};
    #pragma unroll
    for (int ks=0;ks<2;ks++){
      bf16x8 bfr[4];
      #pragma unroll
      for (int ct=0;ct<4;ct++)
        bfr[ct] = *(const bf16x8*)&xT[(ct*16+lr)*72 + ks*32 + lg*8];
      #pragma unroll
      for (int rt=0;rt<2;rt++)
        #pragma unroll
        for (int ct=0;ct<4;ct++)
          qa[rt][ct] = __builtin_amdgcn_mfma_f32_16x16x32_bf16(qfr[rt][ks], bfr[ct], qa[rt][ct], 0,0,0);
    }
    // softmax over 32 head-dim rows per token col
    #pragma unroll
    for (int ct=0;ct<4;ct++){
      float e[2][4]; float p = 0.f;
      #pragma unroll
      for (int rt=0;rt<2;rt++)
        #pragma unroll
        for (int ri=0;ri<4;ri++){ e[rt][ri] = __expf(qa[rt][ct][ri]); p += e[rt][ri]; }
      p += __shfl_xor(p, 16, 64);
      p += __shfl_xor(p, 32, 64);
      const float rinv = 1.f/p;
      const int nn = ct*16 + lr;
      #pragma unroll
      for (int rt=0;rt<2;rt++){
        bf16x4 pk;
        #pragma unroll
        for (int ri=0;ri<4;ri++) pk[ri] = (bf16)(e[rt][ri]*rinv);
        *(bf16x4*)&qs[nn*136 + w*32 + rt*16 + lg*4] = pk;
      }
    }
    __syncthreads();   // qs ready
    #pragma unroll
    for (int ks=0;ks<4;ks++){
      bf16x8 bq = *(const bf16x8*)&qs[(w*16+lr)*136 + ks*32 + lg*8];
      #pragma unroll
      for (int rt=0;rt<4;rt++){
        bf16x8 a = *(const bf16x8*)&W2s[(rt*16+lr)*136 + ks*32 + lg*8];
        yv[ti][rt] = __builtin_amdgcn_mfma_f32_16x16x32_bf16(a, bq, yv[ti][rt], 0,0,0);
      }
    }
    #pragma unroll
    for (int rt=0;rt<4;rt++)
      #pragma unroll
      for (int ri=0;ri<4;ri++){
        yv[ti][rt][ri] += boutr[rt*4+ri];
        const float val = yv[ti][rt][ri];
        sum += val; ss += val*val;
        if (!COOP){
          const int o = rt*16 + lg*4 + ri;
          yb[(long)o*NTOK + n0 + w*16 + lr] = val;
        }
      }
    __syncthreads();   // PV reads done before next iter's xT/qs writes
  }
  #pragma unroll
  for (int off=1; off<64; off<<=1){
    sum += __shfl_xor(sum, off, 64);
    ss  += __shfl_xor(ss,  off, 64);
  }
  if (l==0){ red[w*2] = sum; red[w*2+1] = ss; }
  __syncthreads();

  if constexpr (COOP){
    if (t==0){
      atomicAdd(&yacc[b*2],   red[0]+red[2]+red[4]+red[6]);
      atomicAdd(&yacc[b*2+1], red[1]+red[3]+red[5]+red[7]);
    }
    cg::this_grid().sync();
    if (t==0){
      const float S = atomicAdd(&yacc[b*2],   0.f);   // device-scope coherent read
      const float Q = atomicAdd(&yacc[b*2+1], 0.f);
      const float inv_n = 1.f/2097152.f;
      const float mu = S*inv_n;
      red[0] = mu;
      red[1] = rsqrtf(Q*inv_n - mu*mu + 1e-5f);
    }
    __syncthreads();
    const float mu = red[0], inv = red[1];
    float A[16], B[16];
    #pragma unroll
    for (int rt=0;rt<4;rt++)
      #pragma unroll
      for (int ri=0;ri<4;ri++){
        const int o = rt*16 + lg*4 + ri;
        A[rt*4+ri] = inv*gamma[o];
        B[rt*4+ri] = beta[o] - mu*A[rt*4+ri];
      }
    #pragma unroll
    for (int ti=0;ti<8;ti++){
      const int n0 = blk*512 + ti*64;
      #pragma unroll
      for (int rt=0;rt<4;rt++)
        #pragma unroll
        for (int ri=0;ri<4;ri++){
          const int o = rt*16 + lg*4 + ri;
          yb[(long)o*NTOK + n0 + w*16 + lr] = yv[ti][rt][ri]*A[rt*4+ri] + B[rt*4+ri];
        }
    }
  } else {
    if (t==0){
      ysum[((long)b*64 + blk)*2]   = red[0]+red[2]+red[4]+red[6];
      ysum[((long)b*64 + blk)*2+1] = red[1]+red[3]+red[5]+red[7];
    }
  }
}

__global__ __launch_bounds__(256,2) void k3_coop(const float* __restrict__ x,
    const float* __restrict__ wqkv, const bf16* __restrict__ W2g,
    const float* __restrict__ bout, float* __restrict__ out,
    float* __restrict__ yacc, const float* __restrict__ gamma,
    const float* __restrict__ beta, float* __restrict__ ysum)
{ k3_body<true>(x, wqkv, W2g, bout, out, yacc, gamma, beta, ysum); }

__global__ __launch_bounds__(256,2) void k3_fb(const float* __restrict__ x,
    const float* __restrict__ wqkv, const bf16* __restrict__ W2g,
    const float* __restrict__ bout, float* __restrict__ out,
    float* __restrict__ yacc, const float* __restrict__ gamma,
    const float* __restrict__ beta, float* __restrict__ ysum)
{ k3_body<false>(x, wqkv, W2g, bout, out, yacc, gamma, beta, ysum); }

// ============ K3b (fallback): per-batch mean / rsqrt(var+eps) ============
__global__ __launch_bounds__(64) void k3b_stats(const float* __restrict__ ysum,
                                                float* __restrict__ musig)
{
  const int b = blockIdx.x, t = threadIdx.x;
  float s = ysum[((long)b*64+t)*2];
  float q = ysum[((long)b*64+t)*2+1];
  #pragma unroll
  for (int off=1; off<64; off<<=1){ s += __shfl_xor(s,off,64); q += __shfl_xor(q,off,64); }
  if (t==0){
    const float inv_n = 1.f/2097152.f;
    const float mu = s*inv_n;
    const float var = q*inv_n - mu*mu;
    musig[b*2]   = mu;
    musig[b*2+1] = rsqrtf(var + 1e-5f);
  }
}

// ============ K4 (fallback): normalize + affine, in place on d_out ============
__global__ __launch_bounds__(256) void k4_norm(float* __restrict__ y,
    const float* __restrict__ musig, const float* __restrict__ gamma,
    const float* __restrict__ beta)
{
  const long idx = ((long)blockIdx.x*256 + threadIdx.x)*4;
  const int b = (int)(idx >> 21);
  const int c = (int)((idx >> 15) & 63);
  const float mu = musig[b*2], inv = musig[b*2+1];
  const float g = gamma[c]*inv, be = beta[c];
  f32x4 v4 = *(const f32x4*)(y + idx);
  #pragma unroll
  for (int j=0;j<4;j++) v4[j] = (v4[j] - mu)*g + be;
  *(f32x4*)(y + idx) = v4;
}

extern "C" void kernel_launch(void* const* d_in, const int* in_sizes, int n_in,
                              void* d_out, int out_size, void* d_ws, size_t ws_size,
                              hipStream_t stream) {
  const float* x     = (const float*)d_in[0];
  const float* wqkv  = (const float*)d_in[1];
  const float* wout  = (const float*)d_in[2];
  const float* bout  = (const float*)d_in[3];
  const float* gamma = (const float*)d_in[4];
  const float* beta  = (const float*)d_in[5];
  float* out = (float*)d_out;
  char* ws = (char*)d_ws;
  if (ws_size < 300000u) return;

  float* ctx  = (float*)(ws + 0);       // [8][4][1024] f32 = 131072 B
  float* s1   = (float*)(ws + 131072);  // [8][128] f32     = 4096 B
  float* yacc = (float*)(ws + 135168);  // [8][2] f32       = 64 B
  bf16*  W2   = (bf16*) (ws + 135424);  // [8][64][128] bf16 = 131072 B
  float* ysum = (float*)(ws + 266496);  // [8][64][2] f32    = 4096 B
  float* musig= (float*)(ws + 270592);  // [8][2] f32

  hipMemsetAsync(ws, 0, 135232, stream);  // zero ctx + s1 + yacc
  k1_ctx <<<dim3(64,8), 256, 0, stream>>>(x, wqkv, ctx, s1);
  k2_w2  <<<dim3(4,8),  256, 0, stream>>>(ctx, s1, wout, W2);

  void* args[9] = {(void*)&x, (void*)&wqkv, (void*)&W2, (void*)&bout, (void*)&out,
                   (void*)&yacc, (void*)&gamma, (void*)&beta, (void*)&ysum};
  hipError_t ce = hipLaunchCooperativeKernel((const void*)k3_coop, dim3(64,8), dim3(256),
                                             args, 0u, stream);
  if (ce != hipSuccess){
    k3_fb    <<<dim3(64,8), 256, 0, stream>>>(x, wqkv, W2, bout, out, yacc, gamma, beta, ysum);
    k3b_stats<<<8, 64, 0, stream>>>(ysum, musig);
    k4_norm  <<<16384, 256, 0, stream>>>(out, musig, gamma, beta);
  }
}

// Round 6
// 100.764 us; speedup vs baseline: 1.4753x; 1.4753x over previous
//
#include <hip/hip_runtime.h>

typedef __bf16 bf16;
typedef __bf16 bf16x4 __attribute__((ext_vector_type(4)));
typedef __bf16 bf16x8 __attribute__((ext_vector_type(8)));
typedef float f32x4 __attribute__((ext_vector_type(4)));

#define NTOK 32768
#define SCALE_F 0.17677669529663689f

// ============ K1: k/v proj (transposed) + exp(k) + ctx^T + S1, atomic-reduced ============
// grid (64, 8b), 256 thr, 8 subtiles of 64 tokens. Prefetched x loads, native bf16 casts.
// (unchanged from round 5 — measured ~30 us)
__global__ __launch_bounds__(256) void k1_ctx(const float* __restrict__ x,
    const float* __restrict__ wqkv, float* __restrict__ ctx, float* __restrict__ s1)
{
  const int b = blockIdx.y, chunk = blockIdx.x;
  const int t = threadIdx.x, w = t>>6, l = t&63, lr = l&15, lg = l>>4;
  __shared__ bf16 xT[64*72];    // [n][c]
  __shared__ bf16 ek[128*72];   // [k-ch][n]  exp(k)
  __shared__ bf16 vl[128*72];   // [v-ch][n]  v

  bf16x8 bw[4][2];
  #pragma unroll
  for (int ct=0;ct<4;ct++)
    #pragma unroll
    for (int ks=0;ks<2;ks++){
      const float* src = wqkv + (128 + w*64 + ct*16 + lr)*64 + ks*32 + lg*8;
      #pragma unroll
      for (int j=0;j<8;j++) bw[ct][ks][j] = (bf16)src[j];
    }
  bf16x8 ones;
  #pragma unroll
  for (int j=0;j<8;j++) ones[j] = (bf16)1.0f;

  f32x4 ctxa[2][2]; f32x4 s1a[2];
  #pragma unroll
  for (int i=0;i<2;i++){
    s1a[i] = f32x4{0.f,0.f,0.f,0.f};
    #pragma unroll
    for (int j=0;j<2;j++) ctxa[i][j] = f32x4{0.f,0.f,0.f,0.f};
  }
  const float* xb = x + (long)b*64*NTOK;
  bf16* dst = (w<2) ? ek : vl;
  const int chb = (w&1)*64;
  const bool isk = (w<2);
  const int sn = t&63, cg16 = (t>>6)*16;

  bf16x8 t0, t1;
  {
    const int n0 = chunk*512;
    #pragma unroll
    for (int i=0;i<8;i++) t0[i] = (bf16)xb[(long)(cg16+i)*NTOK + n0 + sn];
    #pragma unroll
    for (int i=0;i<8;i++) t1[i] = (bf16)xb[(long)(cg16+8+i)*NTOK + n0 + sn];
  }

  for (int s=0; s<8; s++) {
    *(bf16x8*)&xT[sn*72 + cg16]     = t0;
    *(bf16x8*)&xT[sn*72 + cg16 + 8] = t1;
    __syncthreads();
    if (s+1 < 8){
      const int n0 = chunk*512 + (s+1)*64;
      #pragma unroll
      for (int i=0;i<8;i++) t0[i] = (bf16)xb[(long)(cg16+i)*NTOK + n0 + sn];
      #pragma unroll
      for (int i=0;i<8;i++) t1[i] = (bf16)xb[(long)(cg16+8+i)*NTOK + n0 + sn];
    }
    f32x4 acc[4][4];
    #pragma unroll
    for (int rt=0;rt<4;rt++)
      #pragma unroll
      for (int ct=0;ct<4;ct++) acc[rt][ct] = f32x4{0.f,0.f,0.f,0.f};
    #pragma unroll
    for (int ks=0;ks<2;ks++){
      bf16x8 af[4];
      #pragma unroll
      for (int rt=0;rt<4;rt++)
        af[rt] = *(const bf16x8*)&xT[(rt*16+lr)*72 + ks*32 + lg*8];
      #pragma unroll
      for (int rt=0;rt<4;rt++)
        #pragma unroll
        for (int ct=0;ct<4;ct++)
          acc[rt][ct] = __builtin_amdgcn_mfma_f32_16x16x32_bf16(af[rt], bw[ct][ks], acc[rt][ct], 0,0,0);
    }
    #pragma unroll
    for (int ct=0;ct<4;ct++){
      const int row = chb + ct*16 + lr;
      #pragma unroll
      for (int rt=0;rt<4;rt++){
        bf16x4 p;
        #pragma unroll
        for (int ri=0;ri<4;ri++){
          const float v = acc[rt][ct][ri];
          p[ri] = isk ? (bf16)__expf(v) : (bf16)v;
        }
        *(bf16x4*)&dst[row*72 + rt*16 + lg*4] = p;
      }
    }
    __syncthreads();
    #pragma unroll
    for (int ks=0;ks<2;ks++){
      bf16x8 bd[2];
      #pragma unroll
      for (int cd=0;cd<2;cd++)
        bd[cd] = *(const bf16x8*)&ek[(w*32 + cd*16 + lr)*72 + ks*32 + lg*8];
      #pragma unroll
      for (int re=0;re<2;re++){
        bf16x8 a = *(const bf16x8*)&vl[(w*32 + re*16 + lr)*72 + ks*32 + lg*8];
        #pragma unroll
        for (int cd=0;cd<2;cd++)
          ctxa[re][cd] = __builtin_amdgcn_mfma_f32_16x16x32_bf16(a, bd[cd], ctxa[re][cd], 0,0,0);
      }
      #pragma unroll
      for (int cd=0;cd<2;cd++)
        s1a[cd] = __builtin_amdgcn_mfma_f32_16x16x32_bf16(ones, bd[cd], s1a[cd], 0,0,0);
    }
  }
  float* cp = ctx + ((long)b*4 + w)*1024;
  #pragma unroll
  for (int re=0;re<2;re++)
    #pragma unroll
    for (int cd=0;cd<2;cd++)
      #pragma unroll
      for (int ri=0;ri<4;ri++){
        const int e = re*16 + lg*4 + ri, d = cd*16 + lr;
        atomicAdd(&cp[e*32 + d], ctxa[re][cd][ri]);
      }
  if (lg==0){
    #pragma unroll
    for (int cd=0;cd<2;cd++)
      atomicAdd(&s1[(long)b*128 + w*32 + cd*16 + lr], s1a[cd][0]);
  }
}

// ============ K2: build W2 = SCALE*w_out*ctx^T/S1 ============
__global__ __launch_bounds__(256) void k2_w2(const float* __restrict__ ctx,
    const float* __restrict__ s1, const float* __restrict__ wout, bf16* __restrict__ W2)
{
  const int b = blockIdx.y, h = blockIdx.x, t = threadIdx.x;
  __shared__ float cs[1024];
  __shared__ float s1s[32];
  {
    f32x4 p4 = *(const f32x4*)(ctx + ((long)b*4 + h)*1024 + t*4);
    *(f32x4*)&cs[t*4] = p4;
  }
  if (t < 32) s1s[t] = s1[(long)b*128 + h*32 + t];
  __syncthreads();
  const int d = t & 31;
  const float rinv = SCALE_F / s1s[d];
  #pragma unroll
  for (int oi=0; oi<8; oi++){
    const int o = (t>>5)*8 + oi;
    float acc = 0.f;
    #pragma unroll
    for (int e=0;e<32;e++) acc += wout[o*128 + h*32 + e] * cs[e*32 + d];
    W2[((long)b*64 + o)*128 + h*32 + d] = (bf16)(acc * rinv);
  }
}

// ============ K3: q-proj + softmax_D + y = W2@qsm + b_out -> ybf (bf16), stats atomics ====
// grid (64, 8b), 256 thr, 8 token-tiles of 64. Streaming stores (no live y state).
__global__ __launch_bounds__(256,2) void k3_y(const float* __restrict__ x,
    const float* __restrict__ wqkv, const bf16* __restrict__ W2g,
    const float* __restrict__ bout, bf16* __restrict__ ybf, float* __restrict__ yacc)
{
  const int b = blockIdx.y, blk = blockIdx.x;
  const int t = threadIdx.x, w = t>>6, l = t&63, lr = l&15, lg = l>>4;
  __shared__ bf16 W2s[64*136];
  __shared__ bf16 xT[64*72];
  __shared__ bf16 qs[64*136];
  __shared__ float red[8];
  const float* xb = x + (long)b*64*NTOK;
  bf16* yb = ybf + (long)b*64*NTOK;

  bf16x8 qfr[2][2];   // q rows w*32 .. w*32+31
  #pragma unroll
  for (int rt=0;rt<2;rt++)
    #pragma unroll
    for (int ks=0;ks<2;ks++){
      const float* src = wqkv + (w*32 + rt*16 + lr)*64 + ks*32 + lg*8;
      #pragma unroll
      for (int j=0;j<8;j++) qfr[rt][ks][j] = (bf16)src[j];
    }
  { // stage W2[b] -> LDS once
    const bf16* src = W2g + (long)b*8192 + t*32;
    const int o = t>>2, c0 = (t&3)*32;
    #pragma unroll
    for (int k=0;k<4;k++)
      *(bf16x8*)&W2s[o*136 + c0 + k*8] = *(const bf16x8*)(src + k*8);
  }
  float boutr[16];
  #pragma unroll
  for (int rt=0;rt<4;rt++)
    #pragma unroll
    for (int ri=0;ri<4;ri++) boutr[rt*4+ri] = bout[rt*16 + lg*4 + ri];

  const int sn = t&63, cg16 = (t>>6)*16;
  bf16x8 t0, t1;
  {
    const int n0 = blk*512;
    #pragma unroll
    for (int i=0;i<8;i++) t0[i] = (bf16)xb[(long)(cg16+i)*NTOK + n0 + sn];
    #pragma unroll
    for (int i=0;i<8;i++) t1[i] = (bf16)xb[(long)(cg16+8+i)*NTOK + n0 + sn];
  }
  float sum=0.f, ss=0.f;

  for (int ti=0; ti<8; ti++){
    const int n0 = blk*512 + ti*64;
    *(bf16x8*)&xT[sn*72 + cg16]     = t0;
    *(bf16x8*)&xT[sn*72 + cg16 + 8] = t1;
    __syncthreads();   // xT (+W2s on ti=0) ready
    if (ti+1 < 8){
      const int nn0 = n0 + 64;
      #pragma unroll
      for (int i=0;i<8;i++) t0[i] = (bf16)xb[(long)(cg16+i)*NTOK + nn0 + sn];
      #pragma unroll
      for (int i=0;i<8;i++) t1[i] = (bf16)xb[(long)(cg16+8+i)*NTOK + nn0 + sn];
    }
    f32x4 qa[2][4];
    #pragma unroll
    for (int rt=0;rt<2;rt++)
      #pragma unroll
      for (int ct=0;ct<4;ct++) qa[rt][ct] = f32x4{0.f,0.f,0.f,0.f};
    #pragma unroll
    for (int ks=0;ks<2;ks++){
      bf16x8 bfr[4];
      #pragma unroll
      for (int ct=0;ct<4;ct++)
        bfr[ct] = *(const bf16x8*)&xT[(ct*16+lr)*72 + ks*32 + lg*8];
      #pragma unroll
      for (int rt=0;rt<2;rt++)
        #pragma unroll
        for (int ct=0;ct<4;ct++)
          qa[rt][ct] = __builtin_amdgcn_mfma_f32_16x16x32_bf16(qfr[rt][ks], bfr[ct], qa[rt][ct], 0,0,0);
    }
    // softmax over 32 head-dim rows per token col
    #pragma unroll
    for (int ct=0;ct<4;ct++){
      float e[2][4]; float p = 0.f;
      #pragma unroll
      for (int rt=0;rt<2;rt++)
        #pragma unroll
        for (int ri=0;ri<4;ri++){ e[rt][ri] = __expf(qa[rt][ct][ri]); p += e[rt][ri]; }
      p += __shfl_xor(p, 16, 64);
      p += __shfl_xor(p, 32, 64);
      const float rinv = 1.f/p;
      const int nn = ct*16 + lr;
      #pragma unroll
      for (int rt=0;rt<2;rt++){
        bf16x4 pk;
        #pragma unroll
        for (int ri=0;ri<4;ri++) pk[ri] = (bf16)(e[rt][ri]*rinv);
        *(bf16x4*)&qs[nn*136 + w*32 + rt*16 + lg*4] = pk;
      }
    }
    __syncthreads();   // qs ready
    f32x4 ya[4];
    #pragma unroll
    for (int rt=0;rt<4;rt++) ya[rt] = f32x4{0.f,0.f,0.f,0.f};
    #pragma unroll
    for (int ks=0;ks<4;ks++){
      bf16x8 bq = *(const bf16x8*)&qs[(w*16+lr)*136 + ks*32 + lg*8];
      #pragma unroll
      for (int rt=0;rt<4;rt++){
        bf16x8 a = *(const bf16x8*)&W2s[(rt*16+lr)*136 + ks*32 + lg*8];
        ya[rt] = __builtin_amdgcn_mfma_f32_16x16x32_bf16(a, bq, ya[rt], 0,0,0);
      }
    }
    #pragma unroll
    for (int rt=0;rt<4;rt++)
      #pragma unroll
      for (int ri=0;ri<4;ri++){
        const int o = rt*16 + lg*4 + ri;
        const float val = ya[rt][ri] + boutr[rt*4+ri];
        sum += val; ss += val*val;
        yb[(long)o*NTOK + n0 + w*16 + lr] = (bf16)val;
      }
    __syncthreads();   // PV reads done before next iter's xT/qs writes
  }
  #pragma unroll
  for (int off=1; off<64; off<<=1){
    sum += __shfl_xor(sum, off, 64);
    ss  += __shfl_xor(ss,  off, 64);
  }
  if (l==0){ red[w*2] = sum; red[w*2+1] = ss; }
  __syncthreads();
  if (t==0){
    atomicAdd(&yacc[b*2],   red[0]+red[2]+red[4]+red[6]);
    atomicAdd(&yacc[b*2+1], red[1]+red[3]+red[5]+red[7]);
  }
}

// ============ K4: normalize + affine, ybf16 -> out f32 ============
__global__ __launch_bounds__(256) void k4_norm(const bf16* __restrict__ ybf,
    const float* __restrict__ yacc, const float* __restrict__ gamma,
    const float* __restrict__ beta, float* __restrict__ out)
{
  const long idx = ((long)blockIdx.x*256 + threadIdx.x)*8;
  const int b = (int)(idx >> 21);
  const int c = (int)((idx >> 15) & 63);
  const float inv_n = 1.f/2097152.f;
  const float mu  = yacc[b*2]*inv_n;
  const float inv = rsqrtf(yacc[b*2+1]*inv_n - mu*mu + 1e-5f);
  const float g = gamma[c]*inv;
  const float be = beta[c] - mu*g;
  bf16x8 v8 = *(const bf16x8*)(ybf + idx);
  f32x4 o0, o1;
  #pragma unroll
  for (int j=0;j<4;j++){ o0[j] = (float)v8[j]*g + be; o1[j] = (float)v8[4+j]*g + be; }
  *(f32x4*)(out + idx)     = o0;
  *(f32x4*)(out + idx + 4) = o1;
}

extern "C" void kernel_launch(void* const* d_in, const int* in_sizes, int n_in,
                              void* d_out, int out_size, void* d_ws, size_t ws_size,
                              hipStream_t stream) {
  const float* x     = (const float*)d_in[0];
  const float* wqkv  = (const float*)d_in[1];
  const float* wout  = (const float*)d_in[2];
  const float* bout  = (const float*)d_in[3];
  const float* gamma = (const float*)d_in[4];
  const float* beta  = (const float*)d_in[5];
  float* out = (float*)d_out;
  char* ws = (char*)d_ws;
  if (ws_size < 33820736u) return;  // ~33.8 MB

  float* ctx  = (float*)(ws + 0);        // [8][4][1024] f32 = 131072 B
  float* s1   = (float*)(ws + 131072);   // [8][128] f32     = 4096 B
  float* yacc = (float*)(ws + 135168);   // [8][2] f32       = 64 B
  bf16*  W2   = (bf16*) (ws + 135232);   // [8][64][128] bf16 = 131072 B
  bf16*  ybf  = (bf16*) (ws + 266304);   // [8][64][32768] bf16 = 33554432 B

  hipMemsetAsync(ws, 0, 135232, stream);  // zero ctx + s1 + yacc
  k1_ctx <<<dim3(64,8), 256, 0, stream>>>(x, wqkv, ctx, s1);
  k2_w2  <<<dim3(4,8),  256, 0, stream>>>(ctx, s1, wout, W2);
  k3_y   <<<dim3(64,8), 256, 0, stream>>>(x, wqkv, W2, bout, ybf, yacc);
  k4_norm<<<8192,       256, 0, stream>>>(ybf, yacc, gamma, beta, out);
}